// Round 4
// baseline (156.206 us; speedup 1.0000x reference)
//
#include <hip/hip_runtime.h>

#define BATCH 16384
#define N1 (BATCH * 196)
#define N2 (BATCH * 49)

// ws layout (bytes):
//   [0,32)                : double stats[4] = {sum1, sumsq1, sum2, sumsq2}
//   [64, 49344)           : wstream: per-wave pair-weight records 8*154*10 floats
//   [49344, 51304)        : wfc1s : w_fc1^T contiguous [49][10]
//   [51312, 63856)        : wk1   : per-pos fused L1 weights [196][16]
//   [63856, 66992)        : wk2   : per-pos fused L2 weights [49][16]
//   [67008, 12912064)     : l1buf BATCH*196 floats
//   [12912064, 16319936)  : l2buf BATCH*52 floats (stride-52 padded)
#define WS_WSTREAM_OFF 64
#define WS_WFC1S_OFF   49344
#define WS_WK1_OFF     51312
#define WS_WK2_OFF     63856
#define WS_L1_OFF      67008
#define WS_L2_OFF      12912064

#define S1 8      // samples per k1 block
#define S2TOT 8   // samples per k2 block

// ---------- compile-time pair index <-> (p,q) ----------
__host__ __device__ constexpr int pair_p(int i) {
    int p = 0, rem = i;
    while (rem >= 49 - p) { rem -= 49 - p; ++p; }
    return p;
}
__host__ __device__ constexpr int pair_q(int i) {
    int p = 0, rem = i;
    while (rem >= 49 - p) { rem -= 49 - p; ++p; }
    return p + rem;
}

__device__ __forceinline__ void block_stats2(float s, float ss, double* stats, int idx,
                                             float* wls, float* wlss) {
    #pragma unroll
    for (int off = 32; off; off >>= 1) {
        s  += __shfl_down(s, off);
        ss += __shfl_down(ss, off);
    }
    int lane = threadIdx.x & 63, wid = threadIdx.x >> 6;
    if (lane == 0) { wls[wid] = s; wlss[wid] = ss; }
    __syncthreads();
    if (threadIdx.x == 0) {
        atomicAdd(&stats[idx],     (double)(wls[0] + wls[1] + wls[2] + wls[3]));
        atomicAdd(&stats[idx + 1], (double)(wlss[0] + wlss[1] + wlss[2] + wlss[3]));
    }
}

// ---------- prep: fuse masks into weights, reorder w_fc2 into per-wave streams ----------
__global__ void __launch_bounds__(256) kprep(
        const float* __restrict__ wf2, const float* __restrict__ wfc1,
        const float* __restrict__ l1w1, const float* __restrict__ wA,
        const float* __restrict__ wB, const float* __restrict__ wC,
        const float* __restrict__ wD, const float* __restrict__ l1w3,
        const float* __restrict__ l2w1, const float* __restrict__ l2w2,
        const float* __restrict__ l2w4,
        float* __restrict__ wstream, float* __restrict__ wfc1s,
        float* __restrict__ wk1, float* __restrict__ wk2) {
    int i = blockIdx.x * 256 + threadIdx.x;
    if (i < 1225) {
        int rem = i, p = 0;
        while (rem >= 49 - p) { rem -= 49 - p; ++p; }
        int q = p + rem;
        int col = p * 49 + q;
        int slot = ((i & 7) * 154 + (i >> 3)) * 10;
        #pragma unroll
        for (int o = 0; o < 10; ++o) wstream[slot + o] = wf2[o * 2401 + col];
    }
    if (i < 196) {
        int pi = i / 14, pj = i - 14 * pi;
        int r0 = 2 * pi * 28 + 2 * pj;
        float* o = wk1 + i * 16;
        o[0] = l1w1[r0];      o[1] = l1w1[r0 + 1];
        o[2] = l1w1[r0 + 28]; o[3] = l1w1[r0 + 29];
        float mA[4] = { pj != 0 ? 1.f : 0.f, pj != 13 ? 1.f : 0.f,
                        pj != 0 ? 1.f : 0.f, pj != 13 ? 1.f : 0.f };
        float mB[4] = { pi != 0 ? 1.f : 0.f, pi != 0 ? 1.f : 0.f,
                        pi != 13 ? 1.f : 0.f, pi != 13 ? 1.f : 0.f };
        const int e1[10] = {0,1,2,3,0,0,0,1,1,2};
        const int e2[10] = {0,1,2,3,1,2,3,2,3,3};
        int wo = pi * 140 + 10 * pj;
        #pragma unroll
        for (int t = 0; t < 10; ++t) {
            float cA = mA[e1[t]] * mA[e2[t]];
            float cB = mB[e1[t]] * mB[e2[t]];
            o[4 + t] = wA[wo + t] * cA + wB[wo + t] * cB
                     + wC[wo + t] * cA * cB + wD[wo + t];
        }
        o[14] = l1w3[i];
        o[15] = 0.f;
    }
    if (i < 49) {
        int pi = i / 7, pj = i - 7 * pi;
        int r0 = 2 * pi * 14 + 2 * pj;
        float* o = wk2 + i * 16;
        o[0] = l2w1[r0];      o[1] = l2w1[r0 + 1];
        o[2] = l2w1[r0 + 14]; o[3] = l2w1[r0 + 15];
        #pragma unroll
        for (int t = 0; t < 10; ++t) o[4 + t] = l2w2[pi * 70 + 10 * pj + t];
        o[14] = l2w4[i];
        o[15] = 0.f;
        #pragma unroll
        for (int o2 = 0; o2 < 10; ++o2) wfc1s[i * 10 + o2] = wfc1[o2 * 49 + i];
    }
}

// ---------- layer 1: LDS-staged, coalesced float4 global loads ----------
__global__ void __launch_bounds__(256) k1(const float* __restrict__ x,
                                          const float* __restrict__ wk1,
                                          float* __restrict__ l1out,
                                          double* __restrict__ stats) {
    __shared__ float xs[S1 * 784];   // 25088 B
    __shared__ float wls[4], wlss[4];
    int t = threadIdx.x;
    const float4* src = (const float4*)(x + (size_t)blockIdx.x * (S1 * 784));
    float4* dst = (float4*)xs;
    #pragma unroll
    for (int i = 0; i < 6; ++i) dst[t + 256 * i] = src[t + 256 * i];
    if (t < 32) dst[t + 1536] = src[t + 1536];   // 1568 = 6*256 + 32

    bool active = t < 196;
    int pos = active ? t : 0;
    int pi = pos / 14, pj = pos - 14 * pi;
    const float4* wp = (const float4*)(wk1 + pos * 16);
    float4 a0 = wp[0], a1 = wp[1], a2 = wp[2], a3 = wp[3];
    int r0 = (2 * pi) * 28 + 2 * pj;
    int sbase = blockIdx.x * S1;
    __syncthreads();

    float sum = 0.f, sumsq = 0.f;
    #pragma unroll
    for (int s = 0; s < S1; ++s) {
        const float* xb = xs + s * 784;
        float2 tp = *(const float2*)(xb + r0);
        float2 bo = *(const float2*)(xb + r0 + 28);
        float b00 = tp.x, b01 = tp.y, b10 = bo.x, b11 = bo.y;
        float acc = b00 * a0.x + b01 * a0.y + b10 * a0.z + b11 * a0.w;
        acc += b00 * b00 * a1.x + b01 * b01 * a1.y + b10 * b10 * a1.z + b11 * b11 * a1.w;
        acc += b00 * b01 * a2.x + b00 * b10 * a2.y + b00 * b11 * a2.z + b01 * b10 * a2.w;
        acc += b01 * b11 * a3.x + b10 * b11 * a3.y + a3.z;
        if (active) {
            l1out[(size_t)(sbase + s) * 196 + pos] = acc;
            sum += acc;
            sumsq += acc * acc;
        }
    }
    block_stats2(sum, sumsq, stats, 0, wls, wlss);
}

// ---------- layer 2: LDS-staged, writes stride-52 padded ----------
__global__ void __launch_bounds__(256) k2(const float* __restrict__ l1buf,
                                          const float* __restrict__ wk2,
                                          const float* __restrict__ gamma,
                                          const float* __restrict__ beta,
                                          double* __restrict__ stats,
                                          float* __restrict__ l2out) {
    __shared__ float hs[S2TOT * 196];  // 6272 B
    __shared__ float wls[4], wlss[4];
    double mean = stats[0] * (1.0 / (double)N1);
    double var  = stats[1] * (1.0 / (double)N1) - mean * mean;
    float a1 = (float)((double)gamma[0] / sqrt(var + 1e-5));
    float c1 = beta[0] - (float)mean * a1;

    int t = threadIdx.x;
    const float4* src = (const float4*)(l1buf + (size_t)blockIdx.x * (S2TOT * 196));
    float4* dst = (float4*)hs;
    dst[t] = src[t];                          // 392 = 256 + 136
    if (t < 136) dst[t + 256] = src[t + 256];

    bool active = t < 196;
    int tt = active ? t : 0;
    int sub = tt / 49;
    int pos = tt - 49 * sub;
    int pi = pos / 7, pj = pos - 7 * pi;
    const float4* wp = (const float4*)(wk2 + pos * 16);
    float4 a0 = wp[0], q1 = wp[1], q2 = wp[2], q3 = wp[3];
    int r0 = (2 * pi) * 14 + 2 * pj;
    int sbase = blockIdx.x * S2TOT;
    __syncthreads();

    float sum = 0.f, sumsq = 0.f;
    #pragma unroll
    for (int s = 0; s < S2TOT / 4; ++s) {
        int sl = s * 4 + sub;
        const float* hb = hs + sl * 196;
        float2 tp = *(const float2*)(hb + r0);
        float2 bo = *(const float2*)(hb + r0 + 14);
        float h00 = fmaf(a1, tp.x, c1), h01 = fmaf(a1, tp.y, c1);
        float h10 = fmaf(a1, bo.x, c1), h11 = fmaf(a1, bo.y, c1);
        float acc = h00 * a0.x + h01 * a0.y + h10 * a0.z + h11 * a0.w;
        acc += h00 * h00 * q1.x + h01 * h01 * q1.y + h10 * h10 * q1.z + h11 * h11 * q1.w;
        acc += h00 * h01 * q2.x + h00 * h10 * q2.y + h00 * h11 * q2.z + h01 * h10 * q2.w;
        acc += h01 * h11 * q3.x + h10 * h11 * q3.y + q3.z;
        if (active) {
            l2out[(size_t)(sbase + sl) * 52 + pos] = acc;
            sum += acc;
            sumsq += acc * acc;
        }
    }
    block_stats2(sum, sumsq, stats, 2, wls, wlss);
}

// ---------- FC: template-unrolled pair stream, weights via scalar loads ----------
template<int W, int J>
__device__ __forceinline__ void fc2_steps(const float* __restrict__ wb,
                                          const float* v, float* acc) {
    constexpr int i = J * 8 + W;
    if constexpr (i < 1225) {
        constexpr int p = pair_p(i);
        constexpr int q = pair_q(i);
        float pv = v[p] * v[q];
        const float* w = wb + J * 10;
        #pragma unroll
        for (int o = 0; o < 10; ++o) acc[o] = fmaf(pv, w[o], acc[o]);
        fc2_steps<W, J + 1>(wb, v, acc);
    }
}

template<int W>
__device__ __forceinline__ void fc_all(const float* __restrict__ wstream,
                                       const float* __restrict__ wfc1s,
                                       const float* v, float* acc) {
    #pragma unroll
    for (int k = 0; k < 49; ++k) {
        if ((k & 7) == W) {
            const float* w = wfc1s + k * 10;
            #pragma unroll
            for (int o = 0; o < 10; ++o) acc[o] = fmaf(v[k], w[o], acc[o]);
        }
    }
    fc2_steps<W, 0>(wstream + W * 1540, v, acc);
}

__global__ void __launch_bounds__(512) k3(const float* __restrict__ l2buf,
                                          const float* __restrict__ wstream,
                                          const float* __restrict__ wfc1s,
                                          const float* __restrict__ b_fc1,
                                          const float* __restrict__ b_fc2,
                                          const float* __restrict__ gamma,
                                          const float* __restrict__ beta,
                                          const double* __restrict__ stats,
                                          float* __restrict__ out) {
    __shared__ float part[8][64][10];
    double mean = stats[2] * (1.0 / (double)N2);
    double var  = stats[3] * (1.0 / (double)N2) - mean * mean;
    float a2 = (float)((double)gamma[0] / sqrt(var + 1e-5));
    float c2 = beta[0] - (float)mean * a2;

    int t = threadIdx.x;
    int lane = t & 63;
    int wid  = t >> 6;
    int s = blockIdx.x * 64 + lane;

    float v[52];
    const float4* src = (const float4*)(l2buf + (size_t)s * 52);
    #pragma unroll
    for (int k = 0; k < 13; ++k) *(float4*)(v + 4 * k) = src[k];
    #pragma unroll
    for (int k = 0; k < 49; ++k) v[k] = fmaf(a2, v[k], c2);

    float acc[10];
    #pragma unroll
    for (int o = 0; o < 10; ++o) acc[o] = 0.f;

    int wu = __builtin_amdgcn_readfirstlane(wid);
    switch (wu) {
        case 0: fc_all<0>(wstream, wfc1s, v, acc); break;
        case 1: fc_all<1>(wstream, wfc1s, v, acc); break;
        case 2: fc_all<2>(wstream, wfc1s, v, acc); break;
        case 3: fc_all<3>(wstream, wfc1s, v, acc); break;
        case 4: fc_all<4>(wstream, wfc1s, v, acc); break;
        case 5: fc_all<5>(wstream, wfc1s, v, acc); break;
        case 6: fc_all<6>(wstream, wfc1s, v, acc); break;
        default: fc_all<7>(wstream, wfc1s, v, acc); break;
    }

    #pragma unroll
    for (int o = 0; o < 10; ++o) part[wid][lane][o] = acc[o];
    __syncthreads();

    for (int idx = t; idx < 640; idx += 512) {
        int sl = idx / 10, o = idx - 10 * sl;
        float r = part[0][sl][o] + part[1][sl][o] + part[2][sl][o] + part[3][sl][o]
                + part[4][sl][o] + part[5][sl][o] + part[6][sl][o] + part[7][sl][o];
        out[(size_t)(blockIdx.x * 64 + sl) * 10 + o] = r + b_fc1[o] + b_fc2[o];
    }
}

extern "C" void kernel_launch(void* const* d_in, const int* in_sizes, int n_in,
                              void* d_out, int out_size, void* d_ws, size_t ws_size,
                              hipStream_t stream) {
    const float* x       = (const float*)d_in[0];
    const float* l1_w1   = (const float*)d_in[1];
    const float* l1_w2_1 = (const float*)d_in[2];
    const float* l1_w2_2 = (const float*)d_in[3];
    const float* l1_w2_3 = (const float*)d_in[4];
    const float* l1_w2_4 = (const float*)d_in[5];
    const float* l1_w3   = (const float*)d_in[6];
    const float* l2_w1   = (const float*)d_in[7];
    const float* l2_w2   = (const float*)d_in[8];
    const float* l2_w4   = (const float*)d_in[9];
    const float* w_fc1   = (const float*)d_in[10];
    const float* b_fc1   = (const float*)d_in[11];
    const float* w_fc2   = (const float*)d_in[12];
    const float* b_fc2   = (const float*)d_in[13];
    const float* bn_gamma = (const float*)d_in[14];
    const float* bn_beta  = (const float*)d_in[15];

    char* ws = (char*)d_ws;
    double* stats = (double*)ws;
    float* wstream = (float*)(ws + WS_WSTREAM_OFF);
    float* wfc1s   = (float*)(ws + WS_WFC1S_OFF);
    float* wk1     = (float*)(ws + WS_WK1_OFF);
    float* wk2     = (float*)(ws + WS_WK2_OFF);
    float* l1buf   = (float*)(ws + WS_L1_OFF);
    float* l2buf   = (float*)(ws + WS_L2_OFF);
    float* out = (float*)d_out;

    hipMemsetAsync(stats, 0, 32, stream);
    kprep<<<5, 256, 0, stream>>>(w_fc2, w_fc1, l1_w1, l1_w2_1, l1_w2_2, l1_w2_3,
                                 l1_w2_4, l1_w3, l2_w1, l2_w2, l2_w4,
                                 wstream, wfc1s, wk1, wk2);
    k1<<<BATCH / S1, 256, 0, stream>>>(x, wk1, l1buf, stats);
    k2<<<BATCH / S2TOT, 256, 0, stream>>>(l1buf, wk2, bn_gamma, bn_beta, stats, l2buf);
    k3<<<BATCH / 64, 512, 0, stream>>>(l2buf, wstream, wfc1s, b_fc1, b_fc2,
                                       bn_gamma, bn_beta, stats, out);
}

// Round 5
// 70.259 us; speedup vs baseline: 2.2233x; 2.2233x over previous
//
#include <hip/hip_runtime.h>

#define BATCH 16384
#define N1 (BATCH * 196)
#define N2 (BATCH * 49)

// ws layout (bytes):
//   [0, 8192)             : double stats, 2 layers x 64 slots x 64B line (sum,sumsq per slot)
//   [8192, 57472)         : wstream: per-wave pair-weight records 8*154*10 floats
//   [57472, 59432)        : wfc1s : w_fc1^T contiguous [49][10]
//   [59440, 71984)        : wk1   : per-pos fused L1 weights [196][16]
//   [71984, 75120)        : wk2   : per-pos fused L2 weights [49][16]
//   [75136, 12920192)     : l1buf BATCH*196 floats
//   [12920192, 16328064)  : l2buf BATCH*52 floats (stride-52 padded)
#define WS_WSTREAM_OFF 8192
#define WS_WFC1S_OFF   57472
#define WS_WK1_OFF     59440
#define WS_WK2_OFF     71984
#define WS_L1_OFF      75136
#define WS_L2_OFF      12920192

#define S1 8      // samples per k1 block
#define S2TOT 8   // samples per k2 block

// ---------- compile-time pair index <-> (p,q) ----------
__host__ __device__ constexpr int pair_p(int i) {
    int p = 0, rem = i;
    while (rem >= 49 - p) { rem -= 49 - p; ++p; }
    return p;
}
__host__ __device__ constexpr int pair_q(int i) {
    int p = 0, rem = i;
    while (rem >= 49 - p) { rem -= 49 - p; ++p; }
    return p + rem;
}

// block reduce -> one atomicAdd pair into this block's slot (slot = blockIdx&63,
// 64B apart -> 64 independent atomic chains instead of one).
__device__ __forceinline__ void block_stats2(float s, float ss, double* slotp,
                                             float* wls, float* wlss) {
    #pragma unroll
    for (int off = 32; off; off >>= 1) {
        s  += __shfl_down(s, off);
        ss += __shfl_down(ss, off);
    }
    int lane = threadIdx.x & 63, wid = threadIdx.x >> 6;
    if (lane == 0) { wls[wid] = s; wlss[wid] = ss; }
    __syncthreads();
    if (threadIdx.x == 0) {
        atomicAdd(&slotp[0], (double)(wls[0] + wls[1] + wls[2] + wls[3]));
        atomicAdd(&slotp[1], (double)(wlss[0] + wlss[1] + wlss[2] + wlss[3]));
    }
}

// first 64 threads: reduce 64 slots -> (a, c) broadcast via LDS
__device__ __forceinline__ void stats_reduce(const double* __restrict__ layer,
                                             const float* __restrict__ gamma,
                                             const float* __restrict__ beta,
                                             double inv_n, float* bcast) {
    int t = threadIdx.x;
    if (t < 64) {
        double s  = layer[t * 8];
        double ss = layer[t * 8 + 1];
        #pragma unroll
        for (int off = 32; off; off >>= 1) {
            s  += __shfl_xor(s, off);
            ss += __shfl_xor(ss, off);
        }
        if (t == 0) {
            double mean = s * inv_n;
            double var  = ss * inv_n - mean * mean;
            float a = (float)((double)gamma[0] / sqrt(var + 1e-5));
            bcast[0] = a;
            bcast[1] = beta[0] - (float)mean * a;
        }
    }
}

// ---------- prep: fuse masks into weights, reorder w_fc2 into per-wave streams ----------
__global__ void __launch_bounds__(256) kprep(
        const float* __restrict__ wf2, const float* __restrict__ wfc1,
        const float* __restrict__ l1w1, const float* __restrict__ wA,
        const float* __restrict__ wB, const float* __restrict__ wC,
        const float* __restrict__ wD, const float* __restrict__ l1w3,
        const float* __restrict__ l2w1, const float* __restrict__ l2w2,
        const float* __restrict__ l2w4,
        float* __restrict__ wstream, float* __restrict__ wfc1s,
        float* __restrict__ wk1, float* __restrict__ wk2) {
    int i = blockIdx.x * 256 + threadIdx.x;
    if (i < 1225) {
        int rem = i, p = 0;
        while (rem >= 49 - p) { rem -= 49 - p; ++p; }
        int q = p + rem;
        int col = p * 49 + q;
        int slot = ((i & 7) * 154 + (i >> 3)) * 10;
        #pragma unroll
        for (int o = 0; o < 10; ++o) wstream[slot + o] = wf2[o * 2401 + col];
    }
    if (i < 196) {
        int pi = i / 14, pj = i - 14 * pi;
        int r0 = 2 * pi * 28 + 2 * pj;
        float* o = wk1 + i * 16;
        o[0] = l1w1[r0];      o[1] = l1w1[r0 + 1];
        o[2] = l1w1[r0 + 28]; o[3] = l1w1[r0 + 29];
        float mA[4] = { pj != 0 ? 1.f : 0.f, pj != 13 ? 1.f : 0.f,
                        pj != 0 ? 1.f : 0.f, pj != 13 ? 1.f : 0.f };
        float mB[4] = { pi != 0 ? 1.f : 0.f, pi != 0 ? 1.f : 0.f,
                        pi != 13 ? 1.f : 0.f, pi != 13 ? 1.f : 0.f };
        const int e1[10] = {0,1,2,3,0,0,0,1,1,2};
        const int e2[10] = {0,1,2,3,1,2,3,2,3,3};
        int wo = pi * 140 + 10 * pj;
        #pragma unroll
        for (int t = 0; t < 10; ++t) {
            float cA = mA[e1[t]] * mA[e2[t]];
            float cB = mB[e1[t]] * mB[e2[t]];
            o[4 + t] = wA[wo + t] * cA + wB[wo + t] * cB
                     + wC[wo + t] * cA * cB + wD[wo + t];
        }
        o[14] = l1w3[i];
        o[15] = 0.f;
    }
    if (i < 49) {
        int pi = i / 7, pj = i - 7 * pi;
        int r0 = 2 * pi * 14 + 2 * pj;
        float* o = wk2 + i * 16;
        o[0] = l2w1[r0];      o[1] = l2w1[r0 + 1];
        o[2] = l2w1[r0 + 14]; o[3] = l2w1[r0 + 15];
        #pragma unroll
        for (int t = 0; t < 10; ++t) o[4 + t] = l2w2[pi * 70 + 10 * pj + t];
        o[14] = l2w4[i];
        o[15] = 0.f;
        #pragma unroll
        for (int o2 = 0; o2 < 10; ++o2) wfc1s[i * 10 + o2] = wfc1[o2 * 49 + i];
    }
}

// ---------- layer 1: LDS-staged, coalesced float4 global loads ----------
__global__ void __launch_bounds__(256) k1(const float* __restrict__ x,
                                          const float* __restrict__ wk1,
                                          float* __restrict__ l1out,
                                          double* __restrict__ stats) {
    __shared__ float xs[S1 * 784];   // 25088 B
    __shared__ float wls[4], wlss[4];
    int t = threadIdx.x;
    const float4* src = (const float4*)(x + (size_t)blockIdx.x * (S1 * 784));
    float4* dst = (float4*)xs;
    #pragma unroll
    for (int i = 0; i < 6; ++i) dst[t + 256 * i] = src[t + 256 * i];
    if (t < 32) dst[t + 1536] = src[t + 1536];   // 1568 = 6*256 + 32

    bool active = t < 196;
    int pos = active ? t : 0;
    int pi = pos / 14, pj = pos - 14 * pi;
    const float4* wp = (const float4*)(wk1 + pos * 16);
    float4 a0 = wp[0], a1 = wp[1], a2 = wp[2], a3 = wp[3];
    int r0 = (2 * pi) * 28 + 2 * pj;
    int sbase = blockIdx.x * S1;
    __syncthreads();

    float sum = 0.f, sumsq = 0.f;
    #pragma unroll
    for (int s = 0; s < S1; ++s) {
        const float* xb = xs + s * 784;
        float2 tp = *(const float2*)(xb + r0);
        float2 bo = *(const float2*)(xb + r0 + 28);
        float b00 = tp.x, b01 = tp.y, b10 = bo.x, b11 = bo.y;
        float acc = b00 * a0.x + b01 * a0.y + b10 * a0.z + b11 * a0.w;
        acc += b00 * b00 * a1.x + b01 * b01 * a1.y + b10 * b10 * a1.z + b11 * b11 * a1.w;
        acc += b00 * b01 * a2.x + b00 * b10 * a2.y + b00 * b11 * a2.z + b01 * b10 * a2.w;
        acc += b01 * b11 * a3.x + b10 * b11 * a3.y + a3.z;
        if (active) {
            l1out[(size_t)(sbase + s) * 196 + pos] = acc;
            sum += acc;
            sumsq += acc * acc;
        }
    }
    block_stats2(sum, sumsq, stats + (blockIdx.x & 63) * 8, wls, wlss);
}

// ---------- layer 2: LDS-staged, writes stride-52 padded ----------
__global__ void __launch_bounds__(256) k2(const float* __restrict__ l1buf,
                                          const float* __restrict__ wk2,
                                          const float* __restrict__ gamma,
                                          const float* __restrict__ beta,
                                          double* __restrict__ stats,
                                          float* __restrict__ l2out) {
    __shared__ float hs[S2TOT * 196];  // 6272 B
    __shared__ float wls[4], wlss[4];
    __shared__ float bcast[2];
    int t = threadIdx.x;

    // stage l1 tile (coalesced)
    const float4* src = (const float4*)(l1buf + (size_t)blockIdx.x * (S2TOT * 196));
    float4* dst = (float4*)hs;
    dst[t] = src[t];                          // 392 = 256 + 136
    if (t < 136) dst[t + 256] = src[t + 256];

    // reduce layer-0 stats slots -> (a1, c1)
    stats_reduce(stats, gamma, beta, 1.0 / (double)N1, bcast);

    bool active = t < 196;
    int tt = active ? t : 0;
    int sub = tt / 49;
    int pos = tt - 49 * sub;
    int pi = pos / 7, pj = pos - 7 * pi;
    const float4* wp = (const float4*)(wk2 + pos * 16);
    float4 a0 = wp[0], q1 = wp[1], q2 = wp[2], q3 = wp[3];
    int r0 = (2 * pi) * 14 + 2 * pj;
    int sbase = blockIdx.x * S2TOT;
    __syncthreads();
    float a1 = bcast[0], c1 = bcast[1];

    float sum = 0.f, sumsq = 0.f;
    #pragma unroll
    for (int s = 0; s < S2TOT / 4; ++s) {
        int sl = s * 4 + sub;
        const float* hb = hs + sl * 196;
        float2 tp = *(const float2*)(hb + r0);
        float2 bo = *(const float2*)(hb + r0 + 14);
        float h00 = fmaf(a1, tp.x, c1), h01 = fmaf(a1, tp.y, c1);
        float h10 = fmaf(a1, bo.x, c1), h11 = fmaf(a1, bo.y, c1);
        float acc = h00 * a0.x + h01 * a0.y + h10 * a0.z + h11 * a0.w;
        acc += h00 * h00 * q1.x + h01 * h01 * q1.y + h10 * h10 * q1.z + h11 * h11 * q1.w;
        acc += h00 * h01 * q2.x + h00 * h10 * q2.y + h00 * h11 * q2.z + h01 * h10 * q2.w;
        acc += h01 * h11 * q3.x + h10 * h11 * q3.y + q3.z;
        if (active) {
            l2out[(size_t)(sbase + sl) * 52 + pos] = acc;
            sum += acc;
            sumsq += acc * acc;
        }
    }
    block_stats2(sum, sumsq, stats + 512 + (blockIdx.x & 63) * 8, wls, wlss);
}

// ---------- FC: template-unrolled pair stream, weights via scalar loads ----------
template<int W, int J>
__device__ __forceinline__ void fc2_steps(const float* __restrict__ wb,
                                          const float* v, float* acc) {
    constexpr int i = J * 8 + W;
    if constexpr (i < 1225) {
        constexpr int p = pair_p(i);
        constexpr int q = pair_q(i);
        float pv = v[p] * v[q];
        const float* w = wb + J * 10;
        #pragma unroll
        for (int o = 0; o < 10; ++o) acc[o] = fmaf(pv, w[o], acc[o]);
        fc2_steps<W, J + 1>(wb, v, acc);
    }
}

template<int W>
__device__ __forceinline__ void fc_all(const float* __restrict__ wstream,
                                       const float* __restrict__ wfc1s,
                                       const float* v, float* acc) {
    #pragma unroll
    for (int k = 0; k < 49; ++k) {
        if ((k & 7) == W) {
            const float* w = wfc1s + k * 10;
            #pragma unroll
            for (int o = 0; o < 10; ++o) acc[o] = fmaf(v[k], w[o], acc[o]);
        }
    }
    fc2_steps<W, 0>(wstream + W * 1540, v, acc);
}

__global__ void __launch_bounds__(512) k3(const float* __restrict__ l2buf,
                                          const float* __restrict__ wstream,
                                          const float* __restrict__ wfc1s,
                                          const float* __restrict__ b_fc1,
                                          const float* __restrict__ b_fc2,
                                          const float* __restrict__ gamma,
                                          const float* __restrict__ beta,
                                          const double* __restrict__ stats,
                                          float* __restrict__ out) {
    __shared__ float part[8][64][10];
    __shared__ float bcast[2];
    int t = threadIdx.x;
    int lane = t & 63;
    int wid  = t >> 6;
    int s = blockIdx.x * 64 + lane;

    // issue v loads first (latency overlaps the stats reduce)
    float v[52];
    const float4* src = (const float4*)(l2buf + (size_t)s * 52);
    #pragma unroll
    for (int k = 0; k < 13; ++k) *(float4*)(v + 4 * k) = src[k];

    stats_reduce(stats + 512, gamma, beta, 1.0 / (double)N2, bcast);
    __syncthreads();
    float a2 = bcast[0], c2 = bcast[1];

    #pragma unroll
    for (int k = 0; k < 49; ++k) v[k] = fmaf(a2, v[k], c2);

    float acc[10];
    #pragma unroll
    for (int o = 0; o < 10; ++o) acc[o] = 0.f;

    int wu = __builtin_amdgcn_readfirstlane(wid);
    switch (wu) {
        case 0: fc_all<0>(wstream, wfc1s, v, acc); break;
        case 1: fc_all<1>(wstream, wfc1s, v, acc); break;
        case 2: fc_all<2>(wstream, wfc1s, v, acc); break;
        case 3: fc_all<3>(wstream, wfc1s, v, acc); break;
        case 4: fc_all<4>(wstream, wfc1s, v, acc); break;
        case 5: fc_all<5>(wstream, wfc1s, v, acc); break;
        case 6: fc_all<6>(wstream, wfc1s, v, acc); break;
        default: fc_all<7>(wstream, wfc1s, v, acc); break;
    }

    #pragma unroll
    for (int o = 0; o < 10; ++o) part[wid][lane][o] = acc[o];
    __syncthreads();

    for (int idx = t; idx < 640; idx += 512) {
        int sl = idx / 10, o = idx - 10 * sl;
        float r = part[0][sl][o] + part[1][sl][o] + part[2][sl][o] + part[3][sl][o]
                + part[4][sl][o] + part[5][sl][o] + part[6][sl][o] + part[7][sl][o];
        out[(size_t)(blockIdx.x * 64 + sl) * 10 + o] = r + b_fc1[o] + b_fc2[o];
    }
}

extern "C" void kernel_launch(void* const* d_in, const int* in_sizes, int n_in,
                              void* d_out, int out_size, void* d_ws, size_t ws_size,
                              hipStream_t stream) {
    const float* x       = (const float*)d_in[0];
    const float* l1_w1   = (const float*)d_in[1];
    const float* l1_w2_1 = (const float*)d_in[2];
    const float* l1_w2_2 = (const float*)d_in[3];
    const float* l1_w2_3 = (const float*)d_in[4];
    const float* l1_w2_4 = (const float*)d_in[5];
    const float* l1_w3   = (const float*)d_in[6];
    const float* l2_w1   = (const float*)d_in[7];
    const float* l2_w2   = (const float*)d_in[8];
    const float* l2_w4   = (const float*)d_in[9];
    const float* w_fc1   = (const float*)d_in[10];
    const float* b_fc1   = (const float*)d_in[11];
    const float* w_fc2   = (const float*)d_in[12];
    const float* b_fc2   = (const float*)d_in[13];
    const float* bn_gamma = (const float*)d_in[14];
    const float* bn_beta  = (const float*)d_in[15];

    char* ws = (char*)d_ws;
    double* stats  = (double*)ws;
    float* wstream = (float*)(ws + WS_WSTREAM_OFF);
    float* wfc1s   = (float*)(ws + WS_WFC1S_OFF);
    float* wk1     = (float*)(ws + WS_WK1_OFF);
    float* wk2     = (float*)(ws + WS_WK2_OFF);
    float* l1buf   = (float*)(ws + WS_L1_OFF);
    float* l2buf   = (float*)(ws + WS_L2_OFF);
    float* out = (float*)d_out;

    hipMemsetAsync(stats, 0, 8192, stream);
    kprep<<<5, 256, 0, stream>>>(w_fc2, w_fc1, l1_w1, l1_w2_1, l1_w2_2, l1_w2_3,
                                 l1_w2_4, l1_w3, l2_w1, l2_w2, l2_w4,
                                 wstream, wfc1s, wk1, wk2);
    k1<<<BATCH / S1, 256, 0, stream>>>(x, wk1, l1buf, stats);
    k2<<<BATCH / S2TOT, 256, 0, stream>>>(l1buf, wk2, bn_gamma, bn_beta, stats, l2buf);
    k3<<<BATCH / 64, 512, 0, stream>>>(l2buf, wstream, wfc1s, b_fc1, b_fc2,
                                       bn_gamma, bn_beta, stats, out);
}